// Round 7
// baseline (274.581 us; speedup 1.0000x reference)
//
#include <hip/hip_runtime.h>
#include <math.h>

#define NROWS 65536
#define DIM   512
#define NCLS  64
#define CCAP  1280   // per-class bucket capacity (mean 1024, sd ~32 -> 8 sigma)

typedef __attribute__((ext_vector_type(4))) float f32x4;
typedef __attribute__((ext_vector_type(8))) short s16x8;

// ws layout (4-byte words):
//   [0..32768)      protoSum[64][512] f32   (zeroed)
//   [32768..32832)  cursors[64] i32         (zeroed; == counts after scatter)
//   32832 lossAcc   32833 accAcc   32834 doneCnt   (zeroed)
//   [32836..32900)  p2[64] f32
//   [32912..114832) perm[64*1280] i32
//   [114944..131328) pBf bf16[64*512] in MFMA B-fragment order
#define WS_PROTOSUM 0
#define WS_CURSORS  32768
#define WS_LOSS     32832
#define WS_ACC      32833
#define WS_DONE     32834
#define WS_P2       32836
#define WS_PERM     32912
#define WS_PBF      114944           // byte 459776, 16B aligned
#define MEMSET_WORDS 32835

static __device__ __forceinline__ unsigned short f2bf(float f) {
    unsigned int u = __float_as_uint(f);
    u += 0x7FFF + ((u >> 16) & 1);   // RNE
    return (unsigned short)(u >> 16);
}
static __device__ __forceinline__ float bf2f(unsigned short h) {
    return __uint_as_float(((unsigned int)h) << 16);
}

// 16B global -> LDS DMA (lane l lands at lds + l*16)
static __device__ __forceinline__ void dma16(const void* g, const void* l) {
    __builtin_amdgcn_global_load_lds(
        (const __attribute__((address_space(1))) void*)g,
        (__attribute__((address_space(3))) void*)l, 16, 0, 0);
}

// ---------------- scatter rows into fixed-stride class buckets ------------
__global__ __launch_bounds__(256) void k_scatter(const int* __restrict__ labels,
                                                 int* __restrict__ cursors,
                                                 int* __restrict__ perm) {
    __shared__ int lh[NCLS], lb[NCLS];
    int t = threadIdx.x;
    if (t < NCLS) lh[t] = 0;
    __syncthreads();
    int i = blockIdx.x * 256 + t;
    int lab = labels[i];
    int rank = atomicAdd(&lh[lab], 1);
    __syncthreads();
    if (t < NCLS) lb[t] = atomicAdd(&cursors[t], lh[t]);
    __syncthreads();
    int pos = lb[lab] + rank;
    if (pos < CCAP) perm[lab * CCAP + pos] = i;
}

// ---------------- per-class partial sums, float4 register accumulation ----
// grid = 64 classes x 4 dim-chunks x 8 row-splits = 2048 blocks
__global__ __launch_bounds__(256) void k_psum(const float* __restrict__ emb,
                                              const int* __restrict__ cursors,
                                              const int* __restrict__ perm,
                                              float* __restrict__ protoSum) {
    __shared__ int permS[CCAP];
    __shared__ float4 red[256];
    int t   = threadIdx.x;
    int c   = blockIdx.x >> 5;
    int sub = blockIdx.x & 31;
    int dc  = sub & 3;        // dim chunk (128 dims)
    int rs  = sub >> 2;       // row split 0..7
    int tl  = t & 31;
    int g   = t >> 5;         // 0..7

    int cnt = cursors[c];
    int n = (cnt < CCAP) ? cnt : CCAP;
    for (int i = t; i < n; i += 256) permS[i] = perm[c * CCAP + i];
    __syncthreads();

    const float4* eb = (const float4*)emb + dc * 32 + tl;
    float4 acc = make_float4(0.f, 0.f, 0.f, 0.f);
#pragma unroll 8
    for (int i = rs * 8 + g; i < n; i += 64) {
        int r = permS[i];                       // LDS broadcast
        float4 v = eb[(size_t)r * 128];         // 512B contiguous per row-grp
        acc.x += v.x; acc.y += v.y; acc.z += v.z; acc.w += v.w;
    }
    red[t] = acc;
    __syncthreads();
    if (t < 32) {
        float4 s = red[t];
#pragma unroll
        for (int gg = 1; gg < 8; ++gg) {
            float4 v = red[gg * 32 + t];
            s.x += v.x; s.y += v.y; s.z += v.z; s.w += v.w;
        }
        float* dst = &protoSum[(size_t)c * DIM + dc * 128 + t * 4];
        atomicAdd(dst + 0, s.x);
        atomicAdd(dst + 1, s.y);
        atomicAdd(dst + 2, s.z);
        atomicAdd(dst + 3, s.w);
    }
}

// ---- finalize prototypes: mean -> bf16 B in MFMA fragment order, p2 ------
// pBf layout: shorts idx = (((kc*4+quad)*4+nt)*16 + l15)*8 + j
__global__ __launch_bounds__(512) void k_protofin(const float* __restrict__ protoSum,
                                                  const int* __restrict__ cursors,
                                                  unsigned short* __restrict__ pBf,
                                                  float* __restrict__ p2) {
    int c = blockIdx.x, d = threadIdx.x;
    float mean = protoSum[(size_t)c * DIM + d] / (float)cursors[c];
    unsigned short mb = f2bf(mean);
    int kc = d >> 5, quad = (d >> 3) & 3, j = d & 7;
    int nt = c >> 4, l15 = c & 15;
    pBf[(size_t)(((kc * 4 + quad) * 4 + nt) * 16 + l15) * 8 + j] = mb;
    float mf = bf2f(mb);
    float sq = mf * mf;
#pragma unroll
    for (int o = 32; o > 0; o >>= 1) sq += __shfl_down(sq, o, 64);
    __shared__ float red[8];
    if ((d & 63) == 0) red[d >> 6] = sq;
    __syncthreads();
    if (d == 0) {
        float ss = 0.f;
#pragma unroll
        for (int w = 0; w < 8; ++w) ss += red[w];
        p2[c] = ss;
    }
}

// -------- main: barrier-FREE wave-private DMA pipeline + MFMA -------------
// grid = 1024 x 256; 64 rows/block; wave wv owns rows wv*16..+15 and stages
// ONLY its own rows via global_load_lds into a wave-private triple buffer.
// XOR swizzle (slot = q ^ (row&7)) kills the 128B-stride bank conflicts.
#define LROWS 64
#define LGRID (NROWS / LROWS)
__global__ __launch_bounds__(256) void k_logits(const float* __restrict__ emb,
                                                const int* __restrict__ labels,
                                                const unsigned short* __restrict__ pBf,
                                                const float* __restrict__ p2,
                                                float* __restrict__ lossAcc,
                                                float* __restrict__ accAcc,
                                                unsigned int* __restrict__ doneCnt,
                                                float* __restrict__ out) {
    __shared__ __align__(16) float Abuf[4][3][16][32];   // 24 KB, wave-private
    __shared__ float rb[8];

    int t    = threadIdx.x;
    int lane = t & 63;
    int wv   = t >> 6;
    int quad = lane >> 4;
    int l15  = lane & 15;
    int rbase = blockIdx.x * LROWS;

    int rw = lane >> 3;    // 0..7: row within DMA call
    int qs = lane & 7;     // LDS quadword slot
    const float4* emb4 = (const float4*)emb;
    // lane's global float4 index for (kc=0, h=0); swizzle q_data = qs ^ rw
    size_t gbase = ((size_t)(rbase + wv * 16 + rw)) * 128 + (size_t)(qs ^ rw);
    const char* lds0 = (const char*)&Abuf[wv][0][0][0];  // wave-uniform

    f32x4 acc[4];
#pragma unroll
    for (int nt = 0; nt < 4; ++nt) acc[nt] = (f32x4){0.f, 0.f, 0.f, 0.f};
    float e2a = 0.f;

    const float4* ar = (const float4*)lds0;  // [buf][row][8 slots]

    // preamble: DMA chunks 0,1; B-frags for chunk 0
    dma16(emb4 + gbase,        lds0);
    dma16(emb4 + gbase + 1024, lds0 + 1024);
    dma16(emb4 + gbase + 8,        lds0 + 2048);
    dma16(emb4 + gbase + 1024 + 8, lds0 + 2048 + 1024);
    s16x8 bfc[4], bfn[4];
#pragma unroll
    for (int nt = 0; nt < 4; ++nt)
        bfc[nt] = *(const s16x8*)(pBf + (size_t)((quad * 4 + nt) * 16 + l15) * 8);

#pragma unroll
    for (int kc = 0; kc < 16; ++kc) {
        const int b = kc % 3;
        // issue next DMA (distance 2) then next B (distance 1)
        if (kc < 14) {
            const int bn = (kc + 2) % 3;
            dma16(emb4 + gbase + (kc + 2) * 8,        lds0 + bn * 2048);
            dma16(emb4 + gbase + 1024 + (kc + 2) * 8, lds0 + bn * 2048 + 1024);
        }
        if (kc < 15) {
#pragma unroll
            for (int nt = 0; nt < 4; ++nt)
                bfn[nt] = *(const s16x8*)(pBf +
                    (size_t)((((kc + 1) * 4 + quad) * 4 + nt) * 16 + l15) * 8);
        }
        // chunk kc's DMA is >= 12 vm-ops deep (asm fences each iteration) ->
        // vmcnt(8) guarantees it has landed; keeps newest prefetches in flight
        if (kc < 15) asm volatile("s_waitcnt vmcnt(8)" ::: "memory");
        else         asm volatile("s_waitcnt vmcnt(0)" ::: "memory");

        // wave-private LDS read: row l15, slots (quad*2+i) ^ (l15&7)
        float4 a0 = ar[b * 128 + l15 * 8 + ((quad * 2)     ^ (l15 & 7))];
        float4 a1 = ar[b * 128 + l15 * 8 + ((quad * 2 + 1) ^ (l15 & 7))];
        e2a += a0.x * a0.x + a0.y * a0.y + a0.z * a0.z + a0.w * a0.w;
        e2a += a1.x * a1.x + a1.y * a1.y + a1.z * a1.z + a1.w * a1.w;
        s16x8 af;
        af[0] = (short)f2bf(a0.x); af[1] = (short)f2bf(a0.y);
        af[2] = (short)f2bf(a0.z); af[3] = (short)f2bf(a0.w);
        af[4] = (short)f2bf(a1.x); af[5] = (short)f2bf(a1.y);
        af[6] = (short)f2bf(a1.z); af[7] = (short)f2bf(a1.w);
#pragma unroll
        for (int nt = 0; nt < 4; ++nt)
            acc[nt] = __builtin_amdgcn_mfma_f32_16x16x32_bf16(af, bfc[nt], acc[nt], 0, 0, 0);
#pragma unroll
        for (int nt = 0; nt < 4; ++nt) bfc[nt] = bfn[nt];
    }

    // e2 per row: sum the 4 quads; afterwards every lane holds row-l15 total
    e2a += __shfl_xor(e2a, 16, 64);
    e2a += __shfl_xor(e2a, 32, 64);

    float p2r[4];
#pragma unroll
    for (int nt = 0; nt < 4; ++nt) p2r[nt] = p2[nt * 16 + l15];

    // epilogue: C/D layout col = nt*16 + l15, row = quad*4 + reg
    float nlls = 0.f, corr = 0.f;
#pragma unroll
    for (int reg = 0; reg < 4; ++reg) {
        int rloc = wv * 16 + quad * 4 + reg;
        float e2v = __shfl(e2a, quad * 4 + reg, 64);   // row's e2 from lane l15=row
        float lg[4];
#pragma unroll
        for (int nt = 0; nt < 4; ++nt) {
            float d2 = e2v + p2r[nt] - 2.f * acc[nt][reg];
            d2 = fmaxf(d2, 1e-12f);
            lg[nt] = -sqrtf(d2);
        }
        float mv = lg[0]; int mc = l15;
#pragma unroll
        for (int nt = 1; nt < 4; ++nt) {
            int cix = nt * 16 + l15;
            if (lg[nt] > mv) { mv = lg[nt]; mc = cix; }
        }
#pragma unroll
        for (int o = 1; o < 16; o <<= 1) {
            float mo = __shfl_xor(mv, o, 64);
            int   co = __shfl_xor(mc, o, 64);
            if (mo > mv || (mo == mv && co < mc)) { mv = mo; mc = co; }
        }
        int lab = labels[rbase + rloc];
        float se = 0.f, ll = 0.f;
#pragma unroll
        for (int nt = 0; nt < 4; ++nt) se += __expf(lg[nt] - mv);
        if ((lab & 15) == l15) ll = lg[lab >> 4];
#pragma unroll
        for (int o = 1; o < 16; o <<= 1) {
            se += __shfl_xor(se, o, 64);
            ll += __shfl_xor(ll, o, 64);
        }
        if (l15 == 0) {
            nlls += __logf(se) + mv - ll;
            corr += (mc == lab) ? 1.f : 0.f;
        }
    }
#pragma unroll
    for (int o = 1; o < 64; o <<= 1) {
        nlls += __shfl_xor(nlls, o, 64);
        corr += __shfl_xor(corr, o, 64);
    }
    if (lane == 0) { rb[wv] = nlls; rb[4 + wv] = corr; }
    __syncthreads();
    if (t == 0) {
        atomicAdd(lossAcc, rb[0] + rb[1] + rb[2] + rb[3]);
        atomicAdd(accAcc, rb[4] + rb[5] + rb[6] + rb[7]);
        __threadfence();
        unsigned int tk = atomicAdd(doneCnt, 1u);
        if (tk == LGRID - 1) {   // last block: all atomics visible
            float ls  = atomicAdd(lossAcc, 0.f);   // device-scope read
            float as_ = atomicAdd(accAcc, 0.f);
            out[0] = ls * (1.f / NROWS);
            out[1] = as_ * (1.f / NROWS);
        }
    }
}

extern "C" void kernel_launch(void* const* d_in, const int* in_sizes, int n_in,
                              void* d_out, int out_size, void* d_ws, size_t ws_size,
                              hipStream_t stream) {
    const float* emb    = (const float*)d_in[0];
    const int*   labels = (const int*)d_in[1];
    float* out = (float*)d_out;

    float* wsf = (float*)d_ws;
    int*   wsi = (int*)d_ws;
    float*          protoSum = wsf + WS_PROTOSUM;
    int*            cursors  = wsi + WS_CURSORS;
    float*          lossAcc  = wsf + WS_LOSS;
    float*          accAcc   = wsf + WS_ACC;
    unsigned int*   doneCnt  = (unsigned int*)(wsi + WS_DONE);
    float*          p2       = wsf + WS_P2;
    int*            perm     = wsi + WS_PERM;
    unsigned short* pBf      = (unsigned short*)(wsf + WS_PBF);

    hipMemsetAsync(d_ws, 0, MEMSET_WORDS * sizeof(int), stream);

    k_scatter<<<NROWS / 256, 256, 0, stream>>>(labels, cursors, perm);
    k_psum<<<NCLS * 32, 256, 0, stream>>>(emb, cursors, perm, protoSum);
    k_protofin<<<NCLS, 512, 0, stream>>>(protoSum, cursors, pBf, p2);
    k_logits<<<LGRID, 256, 0, stream>>>(emb, labels, pBf, p2,
                                        lossAcc, accAcc, doneCnt, out);
}